// Round 8
// baseline (491.824 us; speedup 1.0000x reference)
//
#include <hip/hip_runtime.h>
#include <math.h>

#define B_ 16
#define N_ 4096
#define M_ 1024
#define C1_ 256
#define C2_ 512
#define H_ 256
#define SEC_ 10
#define BN_EPS 1e-5f

typedef _Float16 f16;
typedef f16 f16x8 __attribute__((ext_vector_type(8)));
typedef f16 f16x4 __attribute__((ext_vector_type(4)));
typedef f16 f16x2 __attribute__((ext_vector_type(2)));
typedef float f32x4 __attribute__((ext_vector_type(4)));

// ---------------------------------------------------------------------------
// K1: three_nn — unchanged (exact ordering, 64 queries/block, 4-way m-split)
// ---------------------------------------------------------------------------
__global__ __launch_bounds__(256)
void three_nn_kernel(const float* __restrict__ unknown, const float* __restrict__ known,
                     int* __restrict__ idxp, float* __restrict__ wgtp)
{
    __shared__ float kx[M_], ky[M_], kz[M_];        // 12 KB SoA
    __shared__ float cd[4][64][3];                  // per-wave top-3 distances
    __shared__ int   ci[4][64][3];                  // per-wave top-3 indices
    const int b  = blockIdx.y;
    const int bn = blockIdx.x * 64;
    const int t  = threadIdx.x;
    const float* kb = known + (long)b * M_ * 3;

    {
        const float4 q0 = *(const float4*)(kb + 12*t);
        const float4 q1 = *(const float4*)(kb + 12*t + 4);
        const float4 q2 = *(const float4*)(kb + 12*t + 8);
        const int m = 4*t;
        kx[m+0]=q0.x; ky[m+0]=q0.y; kz[m+0]=q0.z;
        kx[m+1]=q0.w; ky[m+1]=q1.x; kz[m+1]=q1.y;
        kx[m+2]=q1.z; ky[m+2]=q1.w; kz[m+2]=q2.x;
        kx[m+3]=q2.y; ky[m+3]=q2.z; kz[m+3]=q2.w;
    }
    __syncthreads();

    const int w = t >> 6, ln = t & 63;
    const int n = bn + ln;
    const float* up = unknown + ((long)b * N_ + n) * 3;
    const float ux = up[0], uy = up[1], uz = up[2];

    float b0 = 1e30f, b1v = 1e30f, b2v = 1e30f;
    int j0 = 0, j1 = 0, j2 = 0;

    const int m0 = w * 256;
    for (int m = m0; m < m0 + 256; m += 4) {
        const float4 X = *(const float4*)&kx[m];
        const float4 Y = *(const float4*)&ky[m];
        const float4 Z = *(const float4*)&kz[m];
        const float px[4] = {X.x, X.y, X.z, X.w};
        const float py[4] = {Y.x, Y.y, Y.z, Y.w};
        const float pz[4] = {Z.x, Z.y, Z.z, Z.w};
        #pragma unroll
        for (int q = 0; q < 4; q++) {
            const float dx = ux - px[q], dy = uy - py[q], dz = uz - pz[q];
            const float d = dx*dx + dy*dy + dz*dz;
            if (d < b2v) {
                const int mm = m + q;
                if (d < b1v) {
                    b2v = b1v; j2 = j1;
                    if (d < b0) { b1v = b0; j1 = j0; b0 = d; j0 = mm; }
                    else        { b1v = d;  j1 = mm; }
                } else { b2v = d; j2 = mm; }
            }
        }
    }
    cd[w][ln][0] = b0;  cd[w][ln][1] = b1v; cd[w][ln][2] = b2v;
    ci[w][ln][0] = j0;  ci[w][ln][1] = j1;  ci[w][ln][2] = j2;
    __syncthreads();

    if (t < 64) {
        float d0 = cd[0][t][0], d1 = cd[0][t][1], d2 = cd[0][t][2];
        int   i0 = ci[0][t][0], i1 = ci[0][t][1], i2 = ci[0][t][2];
        #pragma unroll
        for (int c = 1; c < 4; c++) {
            #pragma unroll
            for (int j = 0; j < 3; j++) {
                const float d = cd[c][t][j];
                const int  ix = ci[c][t][j];
                if (d < d2) {
                    if (d < d1) {
                        d2 = d1; i2 = i1;
                        if (d < d0) { d1 = d0; i1 = i0; d0 = d; i0 = ix; }
                        else        { d1 = d;  i1 = ix; }
                    } else { d2 = d; i2 = ix; }
                }
            }
        }
        const float r0 = 1.f/(d0 + 1e-8f), r1 = 1.f/(d1 + 1e-8f), r2 = 1.f/(d2 + 1e-8f);
        const float rs = 1.f/(r0 + r1 + r2);
        const long base = ((long)b * N_ + bn + t) * 3;
        idxp[base+0] = i0; idxp[base+1] = i1; idxp[base+2] = i2;
        wgtp[base+0] = r0*rs; wgtp[base+1] = r1*rs; wgtp[base+2] = r2*rs;
    }
}

// ---------------------------------------------------------------------------
// K0: one-shot weight convert fp32 -> fp16 in MFMA-fragment order.
// ---------------------------------------------------------------------------
__global__ __launch_bounds__(256)
void convert_w_kernel(const float* __restrict__ W1, const float* __restrict__ W2,
                      f16* __restrict__ Wf0, f16* __restrict__ Wf1, f16* __restrict__ Wf2)
{
    const int which = blockIdx.y;
    const int K8    = (which == 0) ? 64 : 32;
    const int lda   = (which == 2) ? 256 : 768;
    const float* src = (which == 0) ? W1 : (which == 1) ? (W1 + 512) : W2;
    f16* dst = (which == 0) ? Wf0 : (which == 1) ? Wf1 : Wf2;
    const int t = blockIdx.x * 256 + threadIdx.x;
    const int total = 16 * K8 * 16;
    if (t >= total) return;
    const int l16 = t & 15;
    const int fi  = t >> 4;
    const int k8  = fi & (K8 - 1);
    const int rb  = fi >> ((which == 0) ? 6 : 5);
    const float* s = src + (long)(rb*16 + l16)*lda + k8*8;
    const float4 a = *(const float4*)s;
    const float4 c = *(const float4*)(s + 4);
    f16x8 h;
    h[0]=(f16)a.x; h[1]=(f16)a.y; h[2]=(f16)a.z; h[3]=(f16)a.w;
    h[4]=(f16)c.x; h[5]=(f16)c.y; h[6]=(f16)c.z; h[7]=(f16)c.w;
    *(f16x8*)&dst[(long)t*8] = h;
}

// ---------------------------------------------------------------------------
// fp16-MFMA GEMM — v9: v5 structure with BN=32. Grid doubles (2048 blocks for
// N-tiles, 512 for M-tiles); LDS ~18.4 KB -> 8 blocks/CU capacity; twice the
// resident blocks keep the HBM pipe fed (Little's-law fix via occupancy, not
// scheduling). Wave tile 64h x 32n, acc[4][2].
// MODE 0: store Gt[b][m][h] fp16 (transposed via LDS)
// MODE 1: epilogue gathers interp from Gt into P, acc += P; psum stats
// MODE 2: B staged from fp16 h1 with SE gate; sswl from pre-reduced ssum
// ---------------------------------------------------------------------------
template<int MODE>
__global__ __launch_bounds__(256)
void gemm_mfma(const f16* __restrict__ Af, int K,
               const float* __restrict__ Bf, const f16* __restrict__ Bh,
               long strideB, int ldb,
               f16* __restrict__ Ch, long strideC, int ldc,
               const f16* __restrict__ Gt,
               const int* __restrict__ idxp, const float* __restrict__ wgtp,
               float* __restrict__ psum,
               const float* __restrict__ ssum, const float* __restrict__ rbAdj,
               const float* __restrict__ se_ewp, const float* __restrict__ se_ebp,
               const float* __restrict__ a1p, const float* __restrict__ c1p)
{
    constexpr int TILE = 32 * 72;                  // halves per K-tile buffer
    // aliased: 2 x Bs (2*2304 halves) during k-loop; [32][264] epilogue tile
    __shared__ __align__(16) f16 smem[32*264];
    __shared__ float sswl[SEC_*32];
    f16* const BsA = smem;
    f16* const BsB = smem + TILE;

    const int b   = blockIdx.z;
    const int bn  = blockIdx.x * 32;
    const int tid = threadIdx.x;
    const int l = tid & 63, w = tid >> 6;
    const int lane16 = l & 15, quad = l >> 4;
    const int K8 = K >> 3;

    const float* Bfb = nullptr;
    const f16*   Bhb = nullptr;
    if constexpr (MODE == 2) Bhb = Bh + (long)b*strideB;
    else                     Bfb = Bf + (long)b*strideB;

    if constexpr (MODE == 2) {
        for (int i = tid; i < SEC_*32; i += 256) {
            const int j = i >> 5, nn = i & 31;
            const float v = rbAdj[j] + ssum[((long)b*SEC_ + j)*N_ + bn + nn];
            sswl[j*32 + nn] = v / (1.f + __expf(-v));  // swish
        }
        __syncthreads();
    }

    f32x4 acc[4][2];
    #pragma unroll
    for (int i = 0; i < 4; i++)
        #pragma unroll
        for (int j = 0; j < 2; j++)
            acc[i][j] = (f32x4){0.f, 0.f, 0.f, 0.f};

    // ---- B staging: Bs[n][k] transposed, half2 over k-pairs; one pass ----
    const int k2a = tid >> 3;                      // k-pair 0..31
    const int n0a = (tid & 7) * 4;                 // n 0..28
    auto stageB = [&](int k0, f16* __restrict__ Bsb) {
        if constexpr (MODE == 2) {
            const int ka = k0 + 2*k2a;
            const f16* s0 = Bhb + (long)ka*ldb + bn + n0a;
            const f16x4 ua = *(const f16x4*)s0;
            const f16x4 ub = *(const f16x4*)(s0 + ldb);
            float val[2][4];
            #pragma unroll
            for (int r = 0; r < 2; r++) {
                const int kr = ka + r;
                const float aa = a1p[kr], cc = c1p[kr], eb = se_ebp[kr];
                const float* ew = se_ewp + kr*SEC_;
                #pragma unroll
                for (int j = 0; j < 4; j++) {
                    float e = eb;
                    #pragma unroll
                    for (int q = 0; q < SEC_; q++) e += ew[q]*sswl[q*32 + n0a + j];
                    const float g  = 1.f/(1.f + __expf(-e));
                    const float hv = (r == 0) ? (float)ua[j] : (float)ub[j];
                    val[r][j] = g * (aa*hv + cc);
                }
            }
            #pragma unroll
            for (int j = 0; j < 4; j++) {
                f16x2 p; p[0] = (f16)val[0][j]; p[1] = (f16)val[1][j];
                *(f16x2*)&Bsb[(n0a+j)*72 + 2*k2a] = p;
            }
        } else {
            const float* s0 = Bfb + (long)(k0 + 2*k2a)*ldb + bn + n0a;
            const float4 u = *(const float4*)s0;
            const float4 v = *(const float4*)(s0 + ldb);
            f16x2 p0, p1, p2, p3;
            p0[0]=(f16)u.x; p0[1]=(f16)v.x;
            p1[0]=(f16)u.y; p1[1]=(f16)v.y;
            p2[0]=(f16)u.z; p2[1]=(f16)v.z;
            p3[0]=(f16)u.w; p3[1]=(f16)v.w;
            *(f16x2*)&Bsb[(n0a+0)*72 + 2*k2a] = p0;
            *(f16x2*)&Bsb[(n0a+1)*72 + 2*k2a] = p1;
            *(f16x2*)&Bsb[(n0a+2)*72 + 2*k2a] = p2;
            *(f16x2*)&Bsb[(n0a+3)*72 + 2*k2a] = p3;
        }
    };

    // per-thread invariant part of the A fragment address (halves)
    const f16* Afp = Af + quad*128 + lane16*8;
    const int bbase = lane16*72 + quad*8;

    stageB(0, BsA);
    __syncthreads();

    const int NKT = K >> 6;
    int cur = 0;
    for (int kt = 0; kt < NKT; kt++) {
        f16* const Bcur = cur ? BsB : BsA;
        if (kt + 1 < NKT) stageB((kt+1) << 6, cur ? BsA : BsB);
        #pragma unroll
        for (int s = 0; s < 2; s++) {
            const int ks = kt*2 + s;           // 32-wide k-step index
            f16x8 af[4], bf[2];
            #pragma unroll
            for (int i = 0; i < 4; i++)
                af[i] = *(const f16x8*)(Afp + (long)((w*4 + i)*K8 + ks*4)*128);
            #pragma unroll
            for (int j = 0; j < 2; j++)
                bf[j] = *(const f16x8*)&Bcur[bbase + j*1152 + s*32];
            #pragma unroll
            for (int i = 0; i < 4; i++)
                #pragma unroll
                for (int j = 0; j < 2; j++)
                    acc[i][j] = __builtin_amdgcn_mfma_f32_16x16x32_f16(af[i], bf[j], acc[i][j], 0, 0, 0);
        }
        __syncthreads();   // all reads of Bcur done; next iter may overwrite it
        cur ^= 1;
    }

    // ---- epilogue (smem re-used as [32][264] f16 tile) ----
    if constexpr (MODE == 0) {
        f16* Gl = smem;
        #pragma unroll
        for (int i = 0; i < 4; i++)
            #pragma unroll
            for (int r = 0; r < 4; r++) {
                const int h = w*64 + i*16 + quad*4 + r;
                #pragma unroll
                for (int j = 0; j < 2; j++)
                    Gl[(j*16 + lane16)*264 + h] = (f16)acc[i][j][r];
            }
        __syncthreads();
        f16* Gtb = Ch + (long)b*strideC + (long)bn*H_;
        #pragma unroll
        for (int it = 0; it < 4; it++) {
            const int t = it*256 + tid;
            const int m = t >> 5, c = (t & 31)*8;
            *(f16x8*)&Gtb[m*H_ + c] = *(const f16x8*)&Gl[m*264 + c];
        }
    } else {
        if constexpr (MODE == 1) {
            f16* P = smem;
            const int p  = tid >> 3;            // 0..31 point
            const int qd = tid & 7;             // 0..7 h-block of 32
            const long ib = ((long)b*N_ + bn + p)*3;
            const int i0 = idxp[ib], i1 = idxp[ib+1], i2 = idxp[ib+2];
            const float w0 = wgtp[ib], w1 = wgtp[ib+1], w2 = wgtp[ib+2];
            const f16* gb = Gt + (long)b*M_*H_;
            const f16* g0 = gb + (long)i0*H_ + qd*32;
            const f16* g1 = gb + (long)i1*H_ + qd*32;
            const f16* g2 = gb + (long)i2*H_ + qd*32;
            f16* Pr = P + p*264 + qd*32;
            #pragma unroll
            for (int c = 0; c < 32; c += 8) {
                const f16x8 x0 = *(const f16x8*)&g0[c];
                const f16x8 x1 = *(const f16x8*)&g1[c];
                const f16x8 x2 = *(const f16x8*)&g2[c];
                f16x8 o;
                #pragma unroll
                for (int e = 0; e < 8; e++)
                    o[e] = (f16)(w0*(float)x0[e] + w1*(float)x1[e] + w2*(float)x2[e]);
                *(f16x8*)&Pr[c] = o;
            }
            __syncthreads();
            #pragma unroll
            for (int i = 0; i < 4; i++)
                #pragma unroll
                for (int r = 0; r < 4; r++) {
                    const int h = w*64 + i*16 + quad*4 + r;
                    #pragma unroll
                    for (int j = 0; j < 2; j++)
                        acc[i][j][r] += (float)P[(j*16 + lane16)*264 + h];
                }
        }
        const int bid = blockIdx.z * gridDim.x + blockIdx.x;
        float* ps = psum + (long)bid * (2*H_);
        f16* Cb = Ch + (long)b*strideC;
        #pragma unroll
        for (int i = 0; i < 4; i++)
            #pragma unroll
            for (int r = 0; r < 4; r++) {
                const int row = w*64 + i*16 + quad*4 + r;
                float s1 = 0.f, s2 = 0.f;
                #pragma unroll
                for (int j = 0; j < 2; j++) {
                    const float v = acc[i][j][r];
                    s1 += v; s2 += v*v;
                    Cb[(long)row*ldc + bn + j*16 + lane16] = (f16)v;
                }
                #pragma unroll
                for (int off = 1; off < 16; off <<= 1) {
                    s1 += __shfl_xor(s1, off, 64);
                    s2 += __shfl_xor(s2, off, 64);
                }
                if (lane16 == 0) {
                    ps[row]      = s1;
                    ps[H_ + row] = s2;
                }
            }
    }
}

// ---------------------------------------------------------------------------
__global__ __launch_bounds__(256)
void reduce_stats_kernel(const float* __restrict__ psum, float* __restrict__ stats, int nblk)
{
    __shared__ float red[8][33];
    const int o  = blockIdx.x*32 + (threadIdx.x & 31);
    const int ch = threadIdx.x >> 5;
    float s = 0.f;
    for (int bid = ch; bid < nblk; bid += 8)
        s += psum[(long)bid*(2*H_) + o];
    red[ch][threadIdx.x & 31] = s;
    __syncthreads();
    if (ch == 0) {
        float t = 0.f;
        #pragma unroll
        for (int c = 0; c < 8; c++) t += red[c][threadIdx.x & 31];
        stats[o] = t;
    }
}

// ---------------------------------------------------------------------------
__global__ __launch_bounds__(256)
void finalize1_kernel(const float* __restrict__ stats,
                      const float* __restrict__ g, const float* __restrict__ bb,
                      const float* __restrict__ se_rw, const float* __restrict__ se_rb,
                      float* __restrict__ a1, float* __restrict__ c1,
                      float* __restrict__ rw2, float* __restrict__ rbAdj)
{
    __shared__ float cbuf[H_];
    __shared__ float red[256];
    const int o = threadIdx.x;
    const float inv = 1.f / (float)(B_ * N_);
    const float S1 = stats[o], S2 = stats[H_ + o];
    const float mean = S1 * inv;
    const float var  = S2 * inv - mean*mean;
    const float a = g[o] * rsqrtf(var + BN_EPS);
    const float c = bb[o] - mean*a;
    a1[o] = a; c1[o] = c; cbuf[o] = c;
    for (int j = 0; j < SEC_; j++) rw2[j*H_ + o] = se_rw[j*H_ + o] * a;
    __syncthreads();
    for (int j = 0; j < SEC_; j++) {
        red[o] = se_rw[j*H_ + o] * cbuf[o];
        __syncthreads();
        for (int s = 128; s > 0; s >>= 1) {
            if (o < s) red[o] += red[o + s];
            __syncthreads();
        }
        if (o == 0) rbAdj[j] = se_rb[j] + red[0];
        __syncthreads();
    }
}

// ---------------------------------------------------------------------------
// K5: SE reduce — fully reduced ssum[b][j][n] = sum_o rw2[j][o]*h1[b][o][n].
// ---------------------------------------------------------------------------
__global__ __launch_bounds__(256)
void se_reduce_kernel(const f16* __restrict__ h1h, const float* __restrict__ rw2,
                      float* __restrict__ ssum)
{
    __shared__ float rwl[SEC_][H_];   // 10 KB
    const int b = blockIdx.y;
    const int n = blockIdx.x*256 + threadIdx.x;
    for (int i = threadIdx.x; i < SEC_*H_; i += 256)
        rwl[i >> 8][i & 255] = rw2[i];
    __syncthreads();
    float acc[SEC_];
    #pragma unroll
    for (int j = 0; j < SEC_; j++) acc[j] = 0.f;
    const f16* hp = h1h + (long)b*H_*N_ + n;
    #pragma unroll 8
    for (int o = 0; o < H_; o++) {
        const float hv = (float)hp[(long)o*N_];
        #pragma unroll
        for (int j = 0; j < SEC_; j++) acc[j] += rwl[j][o]*hv;
    }
    #pragma unroll
    for (int j = 0; j < SEC_; j++)
        ssum[((long)b*SEC_ + j)*N_ + n] = acc[j];
}

__global__ __launch_bounds__(256)
void finalize2_kernel(const float* __restrict__ stats,
                      const float* __restrict__ g, const float* __restrict__ bb,
                      float* __restrict__ a2, float* __restrict__ c2)
{
    const int o = threadIdx.x;
    const float inv = 1.f / (float)(B_ * N_);
    const float S1 = stats[o], S2 = stats[H_ + o];
    const float mean = S1 * inv;
    const float var  = S2 * inv - mean*mean;
    const float a = g[o] * rsqrtf(var + BN_EPS);
    a2[o] = a; c2[o] = bb[o] - mean*a;
}

__global__ __launch_bounds__(256)
void bn_relu_kernel(const f16* __restrict__ h2h, float* __restrict__ out,
                    const float* __restrict__ a2, const float* __restrict__ c2)
{
    const long e = ((long)blockIdx.x*256 + threadIdx.x)*8;
    const int o = (int)((e >> 12) & (H_ - 1));
    const f16x8 v = *(const f16x8*)(h2h + e);
    const float a = a2[o], c = c2[o];
    float4 r0, r1;
    r0.x = fmaxf(a*(float)v[0] + c, 0.f);
    r0.y = fmaxf(a*(float)v[1] + c, 0.f);
    r0.z = fmaxf(a*(float)v[2] + c, 0.f);
    r0.w = fmaxf(a*(float)v[3] + c, 0.f);
    r1.x = fmaxf(a*(float)v[4] + c, 0.f);
    r1.y = fmaxf(a*(float)v[5] + c, 0.f);
    r1.z = fmaxf(a*(float)v[6] + c, 0.f);
    r1.w = fmaxf(a*(float)v[7] + c, 0.f);
    *(float4*)(out + e)     = r0;
    *(float4*)(out + e + 4) = r1;
}

// ---------------------------------------------------------------------------
extern "C" void kernel_launch(void* const* d_in, const int* in_sizes, int n_in,
                              void* d_out, int out_size, void* d_ws, size_t ws_size,
                              hipStream_t stream)
{
    const float* unknown = (const float*)d_in[0];
    const float* known   = (const float*)d_in[1];
    const float* uf      = (const float*)d_in[2];
    const float* kf      = (const float*)d_in[3];
    const float* W1      = (const float*)d_in[4];
    const float* g1      = (const float*)d_in[5];
    const float* b1      = (const float*)d_in[6];
    const float* se_rw   = (const float*)d_in[7];
    const float* se_rb   = (const float*)d_in[8];
    const float* se_ew   = (const float*)d_in[9];
    const float* se_eb   = (const float*)d_in[10];
    const float* W2      = (const float*)d_in[11];
    const float* g2      = (const float*)d_in[12];
    const float* b2      = (const float*)d_in[13];

    char* ws = (char*)d_ws;
    size_t off = 0;
    auto alloc = [&](size_t bytes) -> void* {
        void* p = ws + off;
        off += (bytes + 255) & ~(size_t)255;
        return p;
    };
    const int NBLK = (N_/32) * B_;   // 2048 gemm blocks for MODE1/MODE2
    int*   idxp   = (int*)  alloc((size_t)B_*N_*3*4);
    float* wgtp   = (float*)alloc((size_t)B_*N_*3*4);
    f16*   Gt     = (f16*)  alloc((size_t)B_*M_*H_*2);          // 8.4 MB fp16, [b][m][h]
    f16*   h1h    = (f16*)  alloc((size_t)B_*H_*N_*2);          // 33.5 MB fp16
    f16*   h2h    = (f16*)  alloc((size_t)B_*H_*N_*2);          // 33.5 MB fp16
    float* ssum   = (float*)alloc((size_t)B_*SEC_*N_*4);        // 2.6 MB reduced SE
    float* psum1  = (float*)alloc((size_t)NBLK*2*H_*4);         // 4 MB
    float* psum2  = (float*)alloc((size_t)NBLK*2*H_*4);         // 4 MB
    float* stats1 = (float*)alloc(2*H_*4);
    float* stats2 = (float*)alloc(2*H_*4);
    float* a1     = (float*)alloc(H_*4);
    float* c1     = (float*)alloc(H_*4);
    float* rw2    = (float*)alloc(SEC_*H_*4);
    float* rbAdj  = (float*)alloc(64*4);
    float* a2     = (float*)alloc(H_*4);
    float* c2     = (float*)alloc(H_*4);
    f16*   Wf0    = (f16*)  alloc((size_t)H_*C2_*2);            // 256 KB fragment-order
    f16*   Wf1    = (f16*)  alloc((size_t)H_*C1_*2);            // 128 KB
    f16*   Wf2    = (f16*)  alloc((size_t)H_*H_*2);             // 128 KB
    (void)ws_size; (void)in_sizes; (void)n_in; (void)out_size;

    float* out = (float*)d_out;

    // K0: one-shot weight convert to MFMA-fragment-ordered fp16
    convert_w_kernel<<<dim3(64, 3), 256, 0, stream>>>(W1, W2, Wf0, Wf1, Wf2);

    // K1: three_nn (64 queries/block, 4-way m-split, exact ordering)
    three_nn_kernel<<<dim3(N_/64, B_), 256, 0, stream>>>(unknown, known, idxp, wgtp);

    // K2: Gt[b][m][h] = (W1[:, :512] @ kf)^T, fp16
    gemm_mfma<0><<<dim3(M_/32, 1, B_), 256, 0, stream>>>(
        Wf0, C2_, kf, nullptr, (long)C2_*M_, M_,
        Gt, (long)M_*H_, 0,
        nullptr, nullptr, nullptr, nullptr,
        nullptr, nullptr, nullptr, nullptr, nullptr, nullptr);

    // K3: h1 = W1[:, 512:] @ uf + interp(Gt); fp16 store + BN1 partials
    gemm_mfma<1><<<dim3(N_/32, 1, B_), 256, 0, stream>>>(
        Wf1, C1_, uf, nullptr, (long)C1_*N_, N_,
        h1h, (long)H_*N_, N_,
        Gt, idxp, wgtp, psum1,
        nullptr, nullptr, nullptr, nullptr, nullptr, nullptr);

    // K3b: reduce partials -> stats1
    reduce_stats_kernel<<<dim3(16), 256, 0, stream>>>(psum1, stats1, NBLK);

    // K4: BN1 finalize + SE fold
    finalize1_kernel<<<1, 256, 0, stream>>>(stats1, g1, b1, se_rw, se_rb, a1, c1, rw2, rbAdj);

    // K5: SE reduce (fully reduced, no partials)
    se_reduce_kernel<<<dim3(N_/256, B_), 256, 0, stream>>>(h1h, rw2, ssum);

    // K6: conv2 with fused SE expand+sigmoid gate; fp16 store + BN2 partials
    gemm_mfma<2><<<dim3(N_/32, 1, B_), 256, 0, stream>>>(
        Wf2, H_, nullptr, h1h, (long)H_*N_, N_,
        h2h, (long)H_*N_, N_,
        nullptr, nullptr, nullptr, psum2,
        ssum, rbAdj, se_ew, se_eb, a1, c1);

    // K6b: reduce partials -> stats2
    reduce_stats_kernel<<<dim3(16), 256, 0, stream>>>(psum2, stats2, NBLK);

    // K7: BN2 finalize
    finalize2_kernel<<<1, 256, 0, stream>>>(stats2, g2, b2, a2, c2);

    // K8: out = relu(a2*h2 + c2)
    bn_relu_kernel<<<dim3((unsigned)((long)B_*H_*N_/2048)), 256, 0, stream>>>(h2h, out, a2, c2);
}

// Round 9
// 362.014 us; speedup vs baseline: 1.3586x; 1.3586x over previous
//
#include <hip/hip_runtime.h>
#include <math.h>

#define B_ 16
#define N_ 4096
#define M_ 1024
#define C1_ 256
#define C2_ 512
#define H_ 256
#define SEC_ 10
#define PARTS_ 128
#define BN_EPS 1e-5f

typedef _Float16 f16;
typedef f16 f16x8 __attribute__((ext_vector_type(8)));
typedef f16 f16x4 __attribute__((ext_vector_type(4)));
typedef f16 f16x2 __attribute__((ext_vector_type(2)));
typedef float f32x4 __attribute__((ext_vector_type(4)));

// ---------------------------------------------------------------------------
// K1: three_nn — unchanged (exact ordering, 64 queries/block, 4-way m-split)
// ---------------------------------------------------------------------------
__global__ __launch_bounds__(256)
void three_nn_kernel(const float* __restrict__ unknown, const float* __restrict__ known,
                     int* __restrict__ idxp, float* __restrict__ wgtp)
{
    __shared__ float kx[M_], ky[M_], kz[M_];        // 12 KB SoA
    __shared__ float cd[4][64][3];                  // per-wave top-3 distances
    __shared__ int   ci[4][64][3];                  // per-wave top-3 indices
    const int b  = blockIdx.y;
    const int bn = blockIdx.x * 64;
    const int t  = threadIdx.x;
    const float* kb = known + (long)b * M_ * 3;

    {
        const float4 q0 = *(const float4*)(kb + 12*t);
        const float4 q1 = *(const float4*)(kb + 12*t + 4);
        const float4 q2 = *(const float4*)(kb + 12*t + 8);
        const int m = 4*t;
        kx[m+0]=q0.x; ky[m+0]=q0.y; kz[m+0]=q0.z;
        kx[m+1]=q0.w; ky[m+1]=q1.x; kz[m+1]=q1.y;
        kx[m+2]=q1.z; ky[m+2]=q1.w; kz[m+2]=q2.x;
        kx[m+3]=q2.y; ky[m+3]=q2.z; kz[m+3]=q2.w;
    }
    __syncthreads();

    const int w = t >> 6, ln = t & 63;
    const int n = bn + ln;
    const float* up = unknown + ((long)b * N_ + n) * 3;
    const float ux = up[0], uy = up[1], uz = up[2];

    float b0 = 1e30f, b1v = 1e30f, b2v = 1e30f;
    int j0 = 0, j1 = 0, j2 = 0;

    const int m0 = w * 256;
    for (int m = m0; m < m0 + 256; m += 4) {
        const float4 X = *(const float4*)&kx[m];
        const float4 Y = *(const float4*)&ky[m];
        const float4 Z = *(const float4*)&kz[m];
        const float px[4] = {X.x, X.y, X.z, X.w};
        const float py[4] = {Y.x, Y.y, Y.z, Y.w};
        const float pz[4] = {Z.x, Z.y, Z.z, Z.w};
        #pragma unroll
        for (int q = 0; q < 4; q++) {
            const float dx = ux - px[q], dy = uy - py[q], dz = uz - pz[q];
            const float d = dx*dx + dy*dy + dz*dz;
            if (d < b2v) {
                const int mm = m + q;
                if (d < b1v) {
                    b2v = b1v; j2 = j1;
                    if (d < b0) { b1v = b0; j1 = j0; b0 = d; j0 = mm; }
                    else        { b1v = d;  j1 = mm; }
                } else { b2v = d; j2 = mm; }
            }
        }
    }
    cd[w][ln][0] = b0;  cd[w][ln][1] = b1v; cd[w][ln][2] = b2v;
    ci[w][ln][0] = j0;  ci[w][ln][1] = j1;  ci[w][ln][2] = j2;
    __syncthreads();

    if (t < 64) {
        float d0 = cd[0][t][0], d1 = cd[0][t][1], d2 = cd[0][t][2];
        int   i0 = ci[0][t][0], i1 = ci[0][t][1], i2 = ci[0][t][2];
        #pragma unroll
        for (int c = 1; c < 4; c++) {
            #pragma unroll
            for (int j = 0; j < 3; j++) {
                const float d = cd[c][t][j];
                const int  ix = ci[c][t][j];
                if (d < d2) {
                    if (d < d1) {
                        d2 = d1; i2 = i1;
                        if (d < d0) { d1 = d0; i1 = i0; d0 = d; i0 = ix; }
                        else        { d1 = d;  i1 = ix; }
                    } else { d2 = d; i2 = ix; }
                }
            }
        }
        const float r0 = 1.f/(d0 + 1e-8f), r1 = 1.f/(d1 + 1e-8f), r2 = 1.f/(d2 + 1e-8f);
        const float rs = 1.f/(r0 + r1 + r2);
        const long base = ((long)b * N_ + bn + t) * 3;
        idxp[base+0] = i0; idxp[base+1] = i1; idxp[base+2] = i2;
        wgtp[base+0] = r0*rs; wgtp[base+1] = r1*rs; wgtp[base+2] = r2*rs;
    }
}

// ---------------------------------------------------------------------------
// K0: one-shot weight convert fp32 -> fp16 in MFMA-fragment order.
// ---------------------------------------------------------------------------
__global__ __launch_bounds__(256)
void convert_w_kernel(const float* __restrict__ W1, const float* __restrict__ W2,
                      f16* __restrict__ Wf0, f16* __restrict__ Wf1, f16* __restrict__ Wf2)
{
    const int which = blockIdx.y;
    const int K8    = (which == 0) ? 64 : 32;
    const int lda   = (which == 2) ? 256 : 768;
    const float* src = (which == 0) ? W1 : (which == 1) ? (W1 + 512) : W2;
    f16* dst = (which == 0) ? Wf0 : (which == 1) ? Wf1 : Wf2;
    const int t = blockIdx.x * 256 + threadIdx.x;
    const int total = 16 * K8 * 16;
    if (t >= total) return;
    const int l16 = t & 15;
    const int fi  = t >> 4;
    const int k8  = fi & (K8 - 1);
    const int rb  = fi >> ((which == 0) ? 6 : 5);
    const float* s = src + (long)(rb*16 + l16)*lda + k8*8;
    const float4 a = *(const float4*)s;
    const float4 c = *(const float4*)(s + 4);
    f16x8 h;
    h[0]=(f16)a.x; h[1]=(f16)a.y; h[2]=(f16)a.z; h[3]=(f16)a.w;
    h[4]=(f16)c.x; h[5]=(f16)c.y; h[6]=(f16)c.z; h[7]=(f16)c.w;
    *(f16x8*)&dst[(long)t*8] = h;
}

// ---------------------------------------------------------------------------
// fp16-MFMA GEMM — v9: v5 structure with BN=32 (unchanged from round 8).
// ---------------------------------------------------------------------------
template<int MODE>
__global__ __launch_bounds__(256)
void gemm_mfma(const f16* __restrict__ Af, int K,
               const float* __restrict__ Bf, const f16* __restrict__ Bh,
               long strideB, int ldb,
               f16* __restrict__ Ch, long strideC, int ldc,
               const f16* __restrict__ Gt,
               const int* __restrict__ idxp, const float* __restrict__ wgtp,
               float* __restrict__ psum,
               const float* __restrict__ ssum, const float* __restrict__ rbAdj,
               const float* __restrict__ se_ewp, const float* __restrict__ se_ebp,
               const float* __restrict__ a1p, const float* __restrict__ c1p)
{
    constexpr int TILE = 32 * 72;                  // halves per K-tile buffer
    __shared__ __align__(16) f16 smem[32*264];
    __shared__ float sswl[SEC_*32];
    f16* const BsA = smem;
    f16* const BsB = smem + TILE;

    const int b   = blockIdx.z;
    const int bn  = blockIdx.x * 32;
    const int tid = threadIdx.x;
    const int l = tid & 63, w = tid >> 6;
    const int lane16 = l & 15, quad = l >> 4;
    const int K8 = K >> 3;

    const float* Bfb = nullptr;
    const f16*   Bhb = nullptr;
    if constexpr (MODE == 2) Bhb = Bh + (long)b*strideB;
    else                     Bfb = Bf + (long)b*strideB;

    if constexpr (MODE == 2) {
        for (int i = tid; i < SEC_*32; i += 256) {
            const int j = i >> 5, nn = i & 31;
            const float v = rbAdj[j] + ssum[((long)b*SEC_ + j)*N_ + bn + nn];
            sswl[j*32 + nn] = v / (1.f + __expf(-v));  // swish
        }
        __syncthreads();
    }

    f32x4 acc[4][2];
    #pragma unroll
    for (int i = 0; i < 4; i++)
        #pragma unroll
        for (int j = 0; j < 2; j++)
            acc[i][j] = (f32x4){0.f, 0.f, 0.f, 0.f};

    // ---- B staging: Bs[n][k] transposed, half2 over k-pairs; one pass ----
    const int k2a = tid >> 3;                      // k-pair 0..31
    const int n0a = (tid & 7) * 4;                 // n 0..28
    auto stageB = [&](int k0, f16* __restrict__ Bsb) {
        if constexpr (MODE == 2) {
            const int ka = k0 + 2*k2a;
            const f16* s0 = Bhb + (long)ka*ldb + bn + n0a;
            const f16x4 ua = *(const f16x4*)s0;
            const f16x4 ub = *(const f16x4*)(s0 + ldb);
            float val[2][4];
            #pragma unroll
            for (int r = 0; r < 2; r++) {
                const int kr = ka + r;
                const float aa = a1p[kr], cc = c1p[kr], eb = se_ebp[kr];
                const float* ew = se_ewp + kr*SEC_;
                #pragma unroll
                for (int j = 0; j < 4; j++) {
                    float e = eb;
                    #pragma unroll
                    for (int q = 0; q < SEC_; q++) e += ew[q]*sswl[q*32 + n0a + j];
                    const float g  = 1.f/(1.f + __expf(-e));
                    const float hv = (r == 0) ? (float)ua[j] : (float)ub[j];
                    val[r][j] = g * (aa*hv + cc);
                }
            }
            #pragma unroll
            for (int j = 0; j < 4; j++) {
                f16x2 p; p[0] = (f16)val[0][j]; p[1] = (f16)val[1][j];
                *(f16x2*)&Bsb[(n0a+j)*72 + 2*k2a] = p;
            }
        } else {
            const float* s0 = Bfb + (long)(k0 + 2*k2a)*ldb + bn + n0a;
            const float4 u = *(const float4*)s0;
            const float4 v = *(const float4*)(s0 + ldb);
            f16x2 p0, p1, p2, p3;
            p0[0]=(f16)u.x; p0[1]=(f16)v.x;
            p1[0]=(f16)u.y; p1[1]=(f16)v.y;
            p2[0]=(f16)u.z; p2[1]=(f16)v.z;
            p3[0]=(f16)u.w; p3[1]=(f16)v.w;
            *(f16x2*)&Bsb[(n0a+0)*72 + 2*k2a] = p0;
            *(f16x2*)&Bsb[(n0a+1)*72 + 2*k2a] = p1;
            *(f16x2*)&Bsb[(n0a+2)*72 + 2*k2a] = p2;
            *(f16x2*)&Bsb[(n0a+3)*72 + 2*k2a] = p3;
        }
    };

    // per-thread invariant part of the A fragment address (halves)
    const f16* Afp = Af + quad*128 + lane16*8;
    const int bbase = lane16*72 + quad*8;

    stageB(0, BsA);
    __syncthreads();

    const int NKT = K >> 6;
    int cur = 0;
    for (int kt = 0; kt < NKT; kt++) {
        f16* const Bcur = cur ? BsB : BsA;
        if (kt + 1 < NKT) stageB((kt+1) << 6, cur ? BsA : BsB);
        #pragma unroll
        for (int s = 0; s < 2; s++) {
            const int ks = kt*2 + s;           // 32-wide k-step index
            f16x8 af[4], bf[2];
            #pragma unroll
            for (int i = 0; i < 4; i++)
                af[i] = *(const f16x8*)(Afp + (long)((w*4 + i)*K8 + ks*4)*128);
            #pragma unroll
            for (int j = 0; j < 2; j++)
                bf[j] = *(const f16x8*)&Bcur[bbase + j*1152 + s*32];
            #pragma unroll
            for (int i = 0; i < 4; i++)
                #pragma unroll
                for (int j = 0; j < 2; j++)
                    acc[i][j] = __builtin_amdgcn_mfma_f32_16x16x32_f16(af[i], bf[j], acc[i][j], 0, 0, 0);
        }
        __syncthreads();   // all reads of Bcur done; next iter may overwrite it
        cur ^= 1;
    }

    // ---- epilogue (smem re-used as [32][264] f16 tile) ----
    if constexpr (MODE == 0) {
        f16* Gl = smem;
        #pragma unroll
        for (int i = 0; i < 4; i++)
            #pragma unroll
            for (int r = 0; r < 4; r++) {
                const int h = w*64 + i*16 + quad*4 + r;
                #pragma unroll
                for (int j = 0; j < 2; j++)
                    Gl[(j*16 + lane16)*264 + h] = (f16)acc[i][j][r];
            }
        __syncthreads();
        f16* Gtb = Ch + (long)b*strideC + (long)bn*H_;
        #pragma unroll
        for (int it = 0; it < 4; it++) {
            const int t = it*256 + tid;
            const int m = t >> 5, c = (t & 31)*8;
            *(f16x8*)&Gtb[m*H_ + c] = *(const f16x8*)&Gl[m*264 + c];
        }
    } else {
        if constexpr (MODE == 1) {
            f16* P = smem;
            const int p  = tid >> 3;            // 0..31 point
            const int qd = tid & 7;             // 0..7 h-block of 32
            const long ib = ((long)b*N_ + bn + p)*3;
            const int i0 = idxp[ib], i1 = idxp[ib+1], i2 = idxp[ib+2];
            const float w0 = wgtp[ib], w1 = wgtp[ib+1], w2 = wgtp[ib+2];
            const f16* gb = Gt + (long)b*M_*H_;
            const f16* g0 = gb + (long)i0*H_ + qd*32;
            const f16* g1 = gb + (long)i1*H_ + qd*32;
            const f16* g2 = gb + (long)i2*H_ + qd*32;
            f16* Pr = P + p*264 + qd*32;
            #pragma unroll
            for (int c = 0; c < 32; c += 8) {
                const f16x8 x0 = *(const f16x8*)&g0[c];
                const f16x8 x1 = *(const f16x8*)&g1[c];
                const f16x8 x2 = *(const f16x8*)&g2[c];
                f16x8 o;
                #pragma unroll
                for (int e = 0; e < 8; e++)
                    o[e] = (f16)(w0*(float)x0[e] + w1*(float)x1[e] + w2*(float)x2[e]);
                *(f16x8*)&Pr[c] = o;
            }
            __syncthreads();
            #pragma unroll
            for (int i = 0; i < 4; i++)
                #pragma unroll
                for (int r = 0; r < 4; r++) {
                    const int h = w*64 + i*16 + quad*4 + r;
                    #pragma unroll
                    for (int j = 0; j < 2; j++)
                        acc[i][j][r] += (float)P[(j*16 + lane16)*264 + h];
                }
        }
        const int bid = blockIdx.z * gridDim.x + blockIdx.x;
        float* ps = psum + (long)bid * (2*H_);
        f16* Cb = Ch + (long)b*strideC;
        #pragma unroll
        for (int i = 0; i < 4; i++)
            #pragma unroll
            for (int r = 0; r < 4; r++) {
                const int row = w*64 + i*16 + quad*4 + r;
                float s1 = 0.f, s2 = 0.f;
                #pragma unroll
                for (int j = 0; j < 2; j++) {
                    const float v = acc[i][j][r];
                    s1 += v; s2 += v*v;
                    Cb[(long)row*ldc + bn + j*16 + lane16] = (f16)v;
                }
                #pragma unroll
                for (int off = 1; off < 16; off <<= 1) {
                    s1 += __shfl_xor(s1, off, 64);
                    s2 += __shfl_xor(s2, off, 64);
                }
                if (lane16 == 0) {
                    ps[row]      = s1;
                    ps[H_ + row] = s2;
                }
            }
    }
}

// ---------------------------------------------------------------------------
// K3b/K6b stage 1: coalesced partial column-sum of psum[nblk][512].
// 128 blocks x 16 rows; thread t handles cols t and t+256. Fully coalesced.
// ---------------------------------------------------------------------------
__global__ __launch_bounds__(256)
void reduce_stats1_kernel(const float* __restrict__ psum, float* __restrict__ partial,
                          int nblk)
{
    const int chunk = nblk / PARTS_;
    const int r0 = blockIdx.x * chunk;
    const int t  = threadIdx.x;
    float a0 = 0.f, a1 = 0.f;
    #pragma unroll 4
    for (int r = r0; r < r0 + chunk; r++) {
        a0 += psum[(long)r*(2*H_) + t];
        a1 += psum[(long)r*(2*H_) + t + H_];
    }
    partial[(long)blockIdx.x*(2*H_) + t]      = a0;
    partial[(long)blockIdx.x*(2*H_) + t + H_] = a1;
}

// ---------------------------------------------------------------------------
// K4: BN1 finalize + SE fold. Stage-2 stats reduction fused (PARTS_ rows,
// coalesced, L2-resident 256 KB).
// ---------------------------------------------------------------------------
__global__ __launch_bounds__(256)
void finalize1_kernel(const float* __restrict__ partial,
                      const float* __restrict__ g, const float* __restrict__ bb,
                      const float* __restrict__ se_rw, const float* __restrict__ se_rb,
                      float* __restrict__ a1, float* __restrict__ c1,
                      float* __restrict__ rw2, float* __restrict__ rbAdj)
{
    __shared__ float cbuf[H_];
    __shared__ float red[256];
    const int o = threadIdx.x;
    float S1 = 0.f, S2 = 0.f;
    #pragma unroll 4
    for (int r = 0; r < PARTS_; r++) {
        S1 += partial[(long)r*(2*H_) + o];
        S2 += partial[(long)r*(2*H_) + o + H_];
    }
    const float inv = 1.f / (float)(B_ * N_);
    const float mean = S1 * inv;
    const float var  = S2 * inv - mean*mean;
    const float a = g[o] * rsqrtf(var + BN_EPS);
    const float c = bb[o] - mean*a;
    a1[o] = a; c1[o] = c; cbuf[o] = c;
    for (int j = 0; j < SEC_; j++) rw2[j*H_ + o] = se_rw[j*H_ + o] * a;
    __syncthreads();
    for (int j = 0; j < SEC_; j++) {
        red[o] = se_rw[j*H_ + o] * cbuf[o];
        __syncthreads();
        for (int s = 128; s > 0; s >>= 1) {
            if (o < s) red[o] += red[o + s];
            __syncthreads();
        }
        if (o == 0) rbAdj[j] = se_rb[j] + red[0];
        __syncthreads();
    }
}

// ---------------------------------------------------------------------------
// K5: SE reduce — fully reduced ssum[b][j][n] = sum_o rw2[j][o]*h1[b][o][n].
// ---------------------------------------------------------------------------
__global__ __launch_bounds__(256)
void se_reduce_kernel(const f16* __restrict__ h1h, const float* __restrict__ rw2,
                      float* __restrict__ ssum)
{
    __shared__ float rwl[SEC_][H_];   // 10 KB
    const int b = blockIdx.y;
    const int n = blockIdx.x*256 + threadIdx.x;
    for (int i = threadIdx.x; i < SEC_*H_; i += 256)
        rwl[i >> 8][i & 255] = rw2[i];
    __syncthreads();
    float acc[SEC_];
    #pragma unroll
    for (int j = 0; j < SEC_; j++) acc[j] = 0.f;
    const f16* hp = h1h + (long)b*H_*N_ + n;
    #pragma unroll 8
    for (int o = 0; o < H_; o++) {
        const float hv = (float)hp[(long)o*N_];
        #pragma unroll
        for (int j = 0; j < SEC_; j++) acc[j] += rwl[j][o]*hv;
    }
    #pragma unroll
    for (int j = 0; j < SEC_; j++)
        ssum[((long)b*SEC_ + j)*N_ + n] = acc[j];
}

// ---------------------------------------------------------------------------
// K7: BN2 finalize, stage-2 stats reduction fused.
// ---------------------------------------------------------------------------
__global__ __launch_bounds__(256)
void finalize2_kernel(const float* __restrict__ partial,
                      const float* __restrict__ g, const float* __restrict__ bb,
                      float* __restrict__ a2, float* __restrict__ c2)
{
    const int o = threadIdx.x;
    float S1 = 0.f, S2 = 0.f;
    #pragma unroll 4
    for (int r = 0; r < PARTS_; r++) {
        S1 += partial[(long)r*(2*H_) + o];
        S2 += partial[(long)r*(2*H_) + o + H_];
    }
    const float inv = 1.f / (float)(B_ * N_);
    const float mean = S1 * inv;
    const float var  = S2 * inv - mean*mean;
    const float a = g[o] * rsqrtf(var + BN_EPS);
    a2[o] = a; c2[o] = bb[o] - mean*a;
}

__global__ __launch_bounds__(256)
void bn_relu_kernel(const f16* __restrict__ h2h, float* __restrict__ out,
                    const float* __restrict__ a2, const float* __restrict__ c2)
{
    const long e = ((long)blockIdx.x*256 + threadIdx.x)*8;
    const int o = (int)((e >> 12) & (H_ - 1));
    const f16x8 v = *(const f16x8*)(h2h + e);
    const float a = a2[o], c = c2[o];
    float4 r0, r1;
    r0.x = fmaxf(a*(float)v[0] + c, 0.f);
    r0.y = fmaxf(a*(float)v[1] + c, 0.f);
    r0.z = fmaxf(a*(float)v[2] + c, 0.f);
    r0.w = fmaxf(a*(float)v[3] + c, 0.f);
    r1.x = fmaxf(a*(float)v[4] + c, 0.f);
    r1.y = fmaxf(a*(float)v[5] + c, 0.f);
    r1.z = fmaxf(a*(float)v[6] + c, 0.f);
    r1.w = fmaxf(a*(float)v[7] + c, 0.f);
    *(float4*)(out + e)     = r0;
    *(float4*)(out + e + 4) = r1;
}

// ---------------------------------------------------------------------------
extern "C" void kernel_launch(void* const* d_in, const int* in_sizes, int n_in,
                              void* d_out, int out_size, void* d_ws, size_t ws_size,
                              hipStream_t stream)
{
    const float* unknown = (const float*)d_in[0];
    const float* known   = (const float*)d_in[1];
    const float* uf      = (const float*)d_in[2];
    const float* kf      = (const float*)d_in[3];
    const float* W1      = (const float*)d_in[4];
    const float* g1      = (const float*)d_in[5];
    const float* b1      = (const float*)d_in[6];
    const float* se_rw   = (const float*)d_in[7];
    const float* se_rb   = (const float*)d_in[8];
    const float* se_ew   = (const float*)d_in[9];
    const float* se_eb   = (const float*)d_in[10];
    const float* W2      = (const float*)d_in[11];
    const float* g2      = (const float*)d_in[12];
    const float* b2      = (const float*)d_in[13];

    char* ws = (char*)d_ws;
    size_t off = 0;
    auto alloc = [&](size_t bytes) -> void* {
        void* p = ws + off;
        off += (bytes + 255) & ~(size_t)255;
        return p;
    };
    const int NBLK = (N_/32) * B_;   // 2048 gemm blocks for MODE1/MODE2
    int*   idxp   = (int*)  alloc((size_t)B_*N_*3*4);
    float* wgtp   = (float*)alloc((size_t)B_*N_*3*4);
    f16*   Gt     = (f16*)  alloc((size_t)B_*M_*H_*2);          // 8.4 MB fp16, [b][m][h]
    f16*   h1h    = (f16*)  alloc((size_t)B_*H_*N_*2);          // 33.5 MB fp16
    f16*   h2h    = (f16*)  alloc((size_t)B_*H_*N_*2);          // 33.5 MB fp16
    float* ssum   = (float*)alloc((size_t)B_*SEC_*N_*4);        // 2.6 MB reduced SE
    float* psum1  = (float*)alloc((size_t)NBLK*2*H_*4);         // 4 MB
    float* psum2  = (float*)alloc((size_t)NBLK*2*H_*4);         // 4 MB
    float* part1  = (float*)alloc((size_t)PARTS_*2*H_*4);       // 256 KB
    float* part2  = (float*)alloc((size_t)PARTS_*2*H_*4);       // 256 KB
    float* a1     = (float*)alloc(H_*4);
    float* c1     = (float*)alloc(H_*4);
    float* rw2    = (float*)alloc(SEC_*H_*4);
    float* rbAdj  = (float*)alloc(64*4);
    float* a2     = (float*)alloc(H_*4);
    float* c2     = (float*)alloc(H_*4);
    f16*   Wf0    = (f16*)  alloc((size_t)H_*C2_*2);            // 256 KB fragment-order
    f16*   Wf1    = (f16*)  alloc((size_t)H_*C1_*2);            // 128 KB
    f16*   Wf2    = (f16*)  alloc((size_t)H_*H_*2);             // 128 KB
    (void)ws_size; (void)in_sizes; (void)n_in; (void)out_size;

    float* out = (float*)d_out;

    // K0: one-shot weight convert to MFMA-fragment-ordered fp16
    convert_w_kernel<<<dim3(64, 3), 256, 0, stream>>>(W1, W2, Wf0, Wf1, Wf2);

    // K1: three_nn (64 queries/block, 4-way m-split, exact ordering)
    three_nn_kernel<<<dim3(N_/64, B_), 256, 0, stream>>>(unknown, known, idxp, wgtp);

    // K2: Gt[b][m][h] = (W1[:, :512] @ kf)^T, fp16
    gemm_mfma<0><<<dim3(M_/32, 1, B_), 256, 0, stream>>>(
        Wf0, C2_, kf, nullptr, (long)C2_*M_, M_,
        Gt, (long)M_*H_, 0,
        nullptr, nullptr, nullptr, nullptr,
        nullptr, nullptr, nullptr, nullptr, nullptr, nullptr);

    // K3: h1 = W1[:, 512:] @ uf + interp(Gt); fp16 store + BN1 partials
    gemm_mfma<1><<<dim3(N_/32, 1, B_), 256, 0, stream>>>(
        Wf1, C1_, uf, nullptr, (long)C1_*N_, N_,
        h1h, (long)H_*N_, N_,
        Gt, idxp, wgtp, psum1,
        nullptr, nullptr, nullptr, nullptr, nullptr, nullptr);

    // K3b: coalesced partial reduction of psum1
    reduce_stats1_kernel<<<dim3(PARTS_), 256, 0, stream>>>(psum1, part1, NBLK);

    // K4: BN1 finalize (+fused stage-2 reduce) + SE fold
    finalize1_kernel<<<1, 256, 0, stream>>>(part1, g1, b1, se_rw, se_rb, a1, c1, rw2, rbAdj);

    // K5: SE reduce (fully reduced, no partials)
    se_reduce_kernel<<<dim3(N_/256, B_), 256, 0, stream>>>(h1h, rw2, ssum);

    // K6: conv2 with fused SE expand+sigmoid gate; fp16 store + BN2 partials
    gemm_mfma<2><<<dim3(N_/32, 1, B_), 256, 0, stream>>>(
        Wf2, H_, nullptr, h1h, (long)H_*N_, N_,
        h2h, (long)H_*N_, N_,
        nullptr, nullptr, nullptr, psum2,
        ssum, rbAdj, se_ew, se_eb, a1, c1);

    // K6b: coalesced partial reduction of psum2
    reduce_stats1_kernel<<<dim3(PARTS_), 256, 0, stream>>>(psum2, part2, NBLK);

    // K7: BN2 finalize (+fused stage-2 reduce)
    finalize2_kernel<<<1, 256, 0, stream>>>(part2, g2, b2, a2, c2);

    // K8: out = relu(a2*h2 + c2)
    bn_relu_kernel<<<dim3((unsigned)((long)B_*H_*N_/2048)), 256, 0, stream>>>(h2h, out, a2, c2);
}